// Round 7
// baseline (266.272 us; speedup 1.0000x reference)
//
#include <hip/hip_runtime.h>
#include <hip/hip_bf16.h>
#include <stdint.h>

// Problem constants
#define B_   2
#define T_   2048
#define D_   1024
#define H_   16
#define HD_  64
#define MEM_ 512
#define KV_  (MEM_ + T_)   // 2560
#define NIT_ (KV_ / 64)    // 40 kv-tiles of 64
#define NIT2_ (NIT_ / 2)   // 20 per kv-half

using bf16 = __bf16;
typedef __bf16 bf16x8 __attribute__((ext_vector_type(8)));
typedef float  f32x4  __attribute__((ext_vector_type(4)));
typedef short  s16x4  __attribute__((ext_vector_type(4)));
typedef short  s16x8  __attribute__((ext_vector_type(8)));

__device__ __forceinline__ f32x4 mfma16(bf16x8 a, bf16x8 b, f32x4 c) {
  return __builtin_amdgcn_mfma_f32_16x16x32_bf16(a, b, c, 0, 0, 0);
}

// Async global->LDS, 16B per lane (dest = wave-uniform base + lane*16).
__device__ __forceinline__ void gll16(const void* g, void* l) {
  __builtin_amdgcn_global_load_lds(
      (const __attribute__((address_space(1))) unsigned int*)g,
      (__attribute__((address_space(3))) unsigned int*)l, 16, 0, 0);
}

__device__ __forceinline__ unsigned short bf16_bits(float f) {
  bf16 h = (bf16)f;
  return __builtin_bit_cast(unsigned short, h);
}

__device__ __forceinline__ ushort4 pack4(f32x4 v) {
  ushort4 p;
  p.x = bf16_bits(v[0]); p.y = bf16_bits(v[1]);
  p.z = bf16_bits(v[2]); p.w = bf16_bits(v[3]);
  return p;
}

__device__ __forceinline__ bf16x8 cvt8(f32x4 a, f32x4 b) {
  bf16x8 r;
  r[0] = (bf16)a[0]; r[1] = (bf16)a[1]; r[2] = (bf16)a[2]; r[3] = (bf16)a[3];
  r[4] = (bf16)b[0]; r[5] = (bf16)b[1]; r[6] = (bf16)b[2]; r[7] = (bf16)b[3];
  return r;
}

// ---------------------------------------------------------------------------
// prep (fused): blk 0-2047 x conv | 2048-3583 w_qkv conv |
//   3584-3839 memory -> mem_k (row-coalesced) |
//   3840-4095 memory -> mem_vt (column pass, 16B stores) |
//   4096-4607 w_out conv (only when ws has room).
// ---------------------------------------------------------------------------
__global__ void prep(const float* __restrict__ x, const float* __restrict__ wq,
                     const float* __restrict__ memory,
                     const float* __restrict__ wout,
                     bf16* __restrict__ xb, bf16* __restrict__ wqb,
                     bf16* __restrict__ mem_k, bf16* __restrict__ mem_vt,
                     bf16* __restrict__ wob) {
  int blk = blockIdx.x;
  if (blk < 3584) {
    const float* s = (blk < 2048) ? x : wq;
    bf16* d = (blk < 2048) ? xb : wqb;
    size_t i = ((size_t)(blk < 2048 ? blk : blk - 2048) * 256 + threadIdx.x) * 8;
    f32x4 a = *(const f32x4*)(s + i);
    f32x4 b = *(const f32x4*)(s + i + 4);
    *(bf16x8*)(d + i) = cvt8(a, b);
  } else if (blk < 3840) {
    int idx8 = ((blk - 3584) * 256 + threadIdx.x) * 8;   // [0, 512*1024)
    int m = idx8 >> 10, d0 = idx8 & 1023;
    int hh = d0 >> 6, hd0 = d0 & 63;
    f32x4 a = *(const f32x4*)(memory + idx8);
    f32x4 b = *(const f32x4*)(memory + idx8 + 4);
    *(bf16x8*)&mem_k[((size_t)hh * MEM_ + m) * HD_ + hd0] = cvt8(a, b);
  } else if (blk < 4096) {
    int idx = (blk - 3840) * 256 + threadIdx.x;          // [0, 65536)
    int d = idx & 1023;
    int m0 = (idx >> 10) * 8;                            // 0..511 step 8
    bf16x8 r;
#pragma unroll
    for (int j = 0; j < 8; j++)
      r[j] = (bf16)memory[(size_t)(m0 + j) * D_ + d];
    *(bf16x8*)&mem_vt[(size_t)d * MEM_ + m0] = r;
  } else {
    size_t i = ((size_t)(blk - 4096) * 256 + threadIdx.x) * 8;
    f32x4 a = *(const f32x4*)(wout + i);
    f32x4 b = *(const f32x4*)(wout + i + 4);
    *(bf16x8*)(wob + i) = cvt8(a, b);
  }
}

// w_out conv fallback: runs AFTER attn (dest aliases k_ws, dead by then).
__global__ void conv_bf16(const float* __restrict__ s, bf16* __restrict__ d) {
  size_t i = ((size_t)blockIdx.x * 256 + threadIdx.x) * 8;
  f32x4 a = *(const f32x4*)(s + i);
  f32x4 b = *(const f32x4*)(s + i + 4);
  *(bf16x8*)(d + i) = cvt8(a, b);
}

// ---------------------------------------------------------------------------
// GEMM (B^T form): C[M,N] = A[M,K] * W[N,K]^T.  128 x NTILE tile, BK=64
// (32 MFMA per barrier pair), 4 waves (2x2).  global_load_lds w16 staging,
// 16B-chunk XOR swizzle both-sides, bijective XCD swizzle (T1).
// EPI==0: scatter q/k -> [bh][t][64], v -> vt_ws[bh][hd][t] (transposed).
// EPI==1: bias add -> Cout [M][1024] f32.  APLANE: A is plane layout.
// ---------------------------------------------------------------------------
template <int EPI, bool APLANE, int NTILE>
__global__ __launch_bounds__(256, 3) void gemm_bt(
    const bf16* __restrict__ A, const bf16* __restrict__ W,
    const float* __restrict__ bias,
    bf16* __restrict__ q_ws, bf16* __restrict__ k_ws, bf16* __restrict__ vt_ws,
    float* __restrict__ Cout, int K) {
  constexpr int NF = NTILE / 32;        // n-frags per wave
  constexpr int NB = NTILE / 32;        // B-tile gll count
  __shared__ __align__(16) bf16 Als[128 * 64];
  __shared__ __align__(16) bf16 Bls[NTILE * 64];
  char* AB = (char*)Als;
  char* BB = (char*)Bls;
  // Bijective XCD swizzle (nwg % 8 == 0 for both launches).
  const int nwg = gridDim.x * gridDim.y;
  int lin = blockIdx.y * gridDim.x + blockIdx.x;
  lin = (lin & 7) * (nwg >> 3) + (lin >> 3);
  const int m0 = (lin / gridDim.x) * 128;
  const int n0 = (lin % gridDim.x) * NTILE;
  const int tid = threadIdx.x;
  const int w = tid >> 6;
  const int lane = tid & 63;
  const int lx = lane & 15;
  const int quad = lane >> 4;
  const int amb = (w & 1) * 64;
  const int bnb = (w >> 1) * (NTILE / 2);
  const int srow = tid >> 3;                        // 0..31 (+32g per gll)
  const int cs = (tid & 7) ^ (srow & 7);            // swizzled source chunk

  f32x4 acc[4][NF];
#pragma unroll
  for (int i = 0; i < 4; i++)
#pragma unroll
    for (int j = 0; j < NF; j++) acc[i][j] = (f32x4){0.f, 0.f, 0.f, 0.f};

  for (int k0 = 0; k0 < K; k0 += 64) {
    const bf16* pa[4];
#pragma unroll
    for (int g = 0; g < 4; g++) {
      int r = srow + 32 * g;
      if constexpr (APLANE) {
        int hh = k0 >> 6, hd = cs * 8;
        int mA = m0 + r;
        pa[g] = A + ((size_t)((mA >> 11) * H_ + hh) * T_ + (mA & 2047)) * HD_ + hd;
      } else {
        pa[g] = A + (size_t)(m0 + r) * K + k0 + cs * 8;
      }
    }
    const bf16* pb[NB];
#pragma unroll
    for (int g = 0; g < NB; g++)
      pb[g] = W + (size_t)(n0 + srow + 32 * g) * K + k0 + cs * 8;

    __syncthreads();   // prev iteration's LDS reads done
#pragma unroll
    for (int g = 0; g < 4; g++) gll16(pa[g], AB + g * 4096 + tid * 16);
#pragma unroll
    for (int g = 0; g < NB; g++) gll16(pb[g], BB + g * 4096 + tid * 16);
    __syncthreads();   // drains vmcnt -> tiles valid

    bf16x8 af[4][2], bfr[NF][2];
    const int rk = (lx & 7) << 4;   // read-side swizzle key (row&7 == lx&7)
#pragma unroll
    for (int mt = 0; mt < 4; mt++)
#pragma unroll
      for (int kh = 0; kh < 2; kh++)
        af[mt][kh] = *(const bf16x8*)(AB + (size_t)(amb + mt * 16 + lx) * 128 +
                                      ((quad * 16 + kh * 64) ^ rk));
#pragma unroll
    for (int nt = 0; nt < NF; nt++)
#pragma unroll
      for (int kh = 0; kh < 2; kh++)
        bfr[nt][kh] = *(const bf16x8*)(BB + (size_t)(bnb + nt * 16 + lx) * 128 +
                                       ((quad * 16 + kh * 64) ^ rk));
#pragma unroll
    for (int kh = 0; kh < 2; kh++)
#pragma unroll
      for (int mt = 0; mt < 4; mt++)
#pragma unroll
        for (int nt = 0; nt < NF; nt++)
          acc[mt][nt] = mfma16(af[mt][kh], bfr[nt][kh], acc[mt][nt]);
  }

  // Epilogue. C/D layout: row = quad*4+reg (m), col = lane&15 (n).
  if (EPI == 0) {
#pragma unroll
    for (int mt = 0; mt < 4; mt++) {
      int mbase = m0 + amb + mt * 16 + quad * 4;
      int b = mbase >> 11;        // T=2048
      int t = mbase & 2047;
#pragma unroll
      for (int nt = 0; nt < NF; nt++) {
        int col = n0 + bnb + nt * 16 + lx;     // [0,3072)
        int which = col >> 10;                 // 0=q 1=k 2=v
        int d = col & 1023;
        int hh = d >> 6, hdi = d & 63;
        int bh = b * H_ + hh;
        if (which == 0) {
#pragma unroll
          for (int r = 0; r < 4; r++)
            q_ws[((size_t)bh * T_ + t + r) * HD_ + hdi] = (bf16)acc[mt][nt][r];
        } else if (which == 1) {
#pragma unroll
          for (int r = 0; r < 4; r++)
            k_ws[((size_t)bh * T_ + t + r) * HD_ + hdi] = (bf16)acc[mt][nt][r];
        } else {
          // v^T: 4 consecutive t -> one 8B store
          *(ushort4*)&vt_ws[((size_t)bh * HD_ + hdi) * T_ + t] =
              pack4(acc[mt][nt]);
        }
      }
    }
  } else {
#pragma unroll
    for (int nt = 0; nt < NF; nt++) {
      int col = n0 + bnb + nt * 16 + lx;
      float bias_f = bias[col];
#pragma unroll
      for (int mt = 0; mt < 4; mt++) {
        int mbase = m0 + amb + mt * 16 + quad * 4;
#pragma unroll
        for (int r = 0; r < 4; r++)
          Cout[(size_t)(mbase + r) * D_ + col] = acc[mt][nt][r] + bias_f;
      }
    }
  }
}

// ---------------------------------------------------------------------------
// Flash attention, kv-split x2 + CROSS-ITERATION PIPELINE (deferred PV):
// interval t runs QK(t) [MFMA], PV(t-1) [MFMA+LDS, uses pk held from last
// iter -- independent of s(t)], exp(t) [VALU].  This breaks the barrier
// phase-lock (all waves previously did QK / exp / PV in lockstep bursts, so
// MFMA and VALU pipes alternated idle); now exp(t) VALU interleaves with
// PV(t-1) MFMA in the same phase.  V is TRIPLE-buffered so stage(t+1) never
// overwrites V(t-1) ((t+1)%3 != (t-1)%3); K stays double-buffered.
// LDS = 2 halves x (K 2x8K + V 3x8K) = 80 KB -> exactly 2 blocks/CU.
// Loop fully unrolled (NIT2_=20) so pk ping-pong is SSA (rule #20) and all
// LDS offsets are static.  PV skipped at it=0 (uninitialized LDS x 0 can be
// NaN); last PV runs as epilogue.  Ones-MFMA row-sum, full-rate k32 PV.
// 1 block = 128 q of one (b,h); grid 512; output in q_ws.
// ---------------------------------------------------------------------------
__global__ __launch_bounds__(512, 4) void attn_kernel(
    bf16* __restrict__ q_ws, const bf16* __restrict__ k_ws,
    const bf16* __restrict__ vt_ws, const bf16* __restrict__ mem_k,
    const bf16* __restrict__ mem_vt) {
  __shared__ __align__(16) bf16 Kls[2 * 2 * 64 * 64];   // [half][kbuf] 32 KB
  __shared__ __align__(16) bf16 Vls[2 * 3 * 64 * 64];   // [half][vbuf] 48 KB
  char* KB = (char*)Kls;
  char* VB = (char*)Vls;
  const int tid = threadIdx.x;         // 0..511
  const int wh = tid >> 8;             // kv-half
  const int t2 = tid & 255;
  const int w = t2 >> 6;               // wave within half
  const int lane = tid & 63;
  const int lx = lane & 15;
  const int quad = lane >> 4;
  const int bh = blockIdx.x & 31;      // XCD-locality
  const int qt = blockIdx.x >> 5;      // 16 q-tiles of 128
  const int q0 = qt * 128 + w * 32;
  const int h = bh & 15;

  const int srow1 = t2 >> 3;               // 0..31
  const int sc1 = (t2 & 7) ^ (srow1 & 7);  // pre-swizzled source chunk

  char* KBh = KB + wh * 16384;   // 2 bufs x 8 KB
  char* VBh = VB + wh * 24576;   // 3 bufs x 8 KB

  bf16* qbase = q_ws + ((size_t)bh * T_ + q0) * HD_;

  const bf16* kpl = k_ws + (size_t)bh * T_ * HD_;
  const bf16* vpl = vt_ws + (size_t)bh * HD_ * T_;
  const bf16* mkp = mem_k + (size_t)h * MEM_ * HD_;   // per-head plane
  const bf16* mvp = mem_vt + (size_t)h * HD_ * MEM_;

  // Stage this half's kv-tile `it2` into K buf kbi / V buf vbi.
  auto stage = [&](int it2, int kbi, int vbi) {
    const int kv0 = (wh * NIT2_ + it2) * 64;
    const bf16 *kp1, *kp2, *vp1, *vp2;
    if (kv0 < MEM_) {
      kp1 = mkp + (size_t)(kv0 + srow1) * HD_ + sc1 * 8;
      kp2 = kp1 + (size_t)32 * HD_;
      vp1 = mvp + (size_t)srow1 * MEM_ + kv0 + sc1 * 8;
      vp2 = vp1 + (size_t)32 * MEM_;
    } else {
      const int t0 = kv0 - MEM_;
      kp1 = kpl + (size_t)(t0 + srow1) * HD_ + sc1 * 8;
      kp2 = kp1 + (size_t)32 * HD_;
      vp1 = vpl + (size_t)srow1 * T_ + t0 + sc1 * 8;
      vp2 = vp1 + (size_t)32 * T_;
    }
    char* kb = KBh + kbi * 8192;
    char* vb = VBh + vbi * 8192;
    gll16(kp1, kb + t2 * 16);
    gll16(kp2, kb + t2 * 16 + 4096);
    gll16(vp1, vb + t2 * 16);
    gll16(vp2, vb + t2 * 16 + 4096);
  };

  // Q B-frags (k32); fold softmax scale AND log2(e) into Q:
  // s = (q*0.125*log2e) . k  ->  exp2(s) == exp(0.125 * q.k)
  const float QSCALE = 0.125f * 1.44269504089f;
  bf16x8 qf[2][2];
#pragma unroll
  for (int qg = 0; qg < 2; qg++)
#pragma unroll
    for (int hf = 0; hf < 2; hf++) {
      bf16x8 v = *(const bf16x8*)(qbase + (size_t)(qg * 16 + lx) * HD_ +
                                  hf * 32 + quad * 8);
#pragma unroll
      for (int i = 0; i < 8; i++)
        v[i] = (bf16)((float)v[i] * QSCALE);
      qf[qg][hf] = v;
    }

  bf16x8 ones;
#pragma unroll
  for (int i = 0; i < 8; i++) ones[i] = (bf16)1.0f;

  f32x4 o[4][2];
#pragma unroll
  for (int mt = 0; mt < 4; mt++)
#pragma unroll
    for (int qg = 0; qg < 2; qg++) o[mt][qg] = (f32x4){0.f, 0.f, 0.f, 0.f};
  f32x4 osum[2] = {(f32x4){0.f, 0.f, 0.f, 0.f}, (f32x4){0.f, 0.f, 0.f, 0.f}};

  s16x8 pkp[2][2];   // previous tile's P (PV B-frags), SSA via full unroll
  const int sw = (lx & 7) << 4;   // read-side swizzle (row&7 == lx&7)

  // PV for the PREVIOUS tile from V buffer VBp using pkp.
  auto pv_step = [&](const char* VBp) {
#pragma unroll
    for (int mt = 0; mt < 4; mt++) {
      const char* vb = VBp + (size_t)(mt * 16 + lx) * 128;
#pragma unroll
      for (int p = 0; p < 2; p++) {
        // A-frag: V[d][kv] at kv-chunks p*32+quad*4 and p*32+16+quad*4
        s16x4 lo = *(const s16x4*)(vb + ((p * 64 + quad * 8) ^ sw));
        s16x4 hi = *(const s16x4*)(vb + ((p * 64 + 32 + quad * 8) ^ sw));
        s16x8 cat = __builtin_shufflevector(lo, hi, 0, 1, 2, 3, 4, 5, 6, 7);
        bf16x8 va = __builtin_bit_cast(bf16x8, cat);
#pragma unroll
        for (int qg = 0; qg < 2; qg++)
          o[mt][qg] = mfma16(va, __builtin_bit_cast(bf16x8, pkp[qg][p]),
                             o[mt][qg]);
      }
    }
    // denominator: osum[qg] += 1^T . P  (all C rows identical)
#pragma unroll
    for (int p = 0; p < 2; p++)
#pragma unroll
      for (int qg = 0; qg < 2; qg++)
        osum[qg] = mfma16(ones, __builtin_bit_cast(bf16x8, pkp[qg][p]),
                          osum[qg]);
  };

  stage(0, 0, 0);   // prologue prefetch

#pragma unroll
  for (int it = 0; it < NIT2_; it++) {
    const int kc = it & 1;
    const int vprev = (it + 2) % 3;          // == (it-1) % 3
    if (it + 1 < NIT2_) {
      stage(it + 1, kc ^ 1, (it + 1) % 3);
      asm volatile("s_waitcnt vmcnt(4)" ::: "memory");   // cur's 4 loads done
    } else {
      asm volatile("s_waitcnt vmcnt(0)" ::: "memory");
    }
    __builtin_amdgcn_s_barrier();        // all waves' cur parts landed
    __builtin_amdgcn_sched_barrier(0);

    const char* KBc = KBh + kc * 8192;
    f32x4 s[4][2];
    __builtin_amdgcn_s_setprio(1);
    // QK(t)
#pragma unroll
    for (int g = 0; g < 4; g++) {
      const char* kb = KBc + (size_t)(g * 16 + lx) * 128;
      bf16x8 ka0 = *(const bf16x8*)(kb + ((quad * 16) ^ sw));
      bf16x8 ka1 = *(const bf16x8*)(kb + ((64 + quad * 16) ^ sw));
#pragma unroll
      for (int qg = 0; qg < 2; qg++) {
        s[g][qg] = (f32x4){0.f, 0.f, 0.f, 0.f};
        s[g][qg] = mfma16(ka0, qf[qg][0], s[g][qg]);
        s[g][qg] = mfma16(ka1, qf[qg][1], s[g][qg]);
      }
    }
    // PV(t-1): independent of s(t) -> scheduler interleaves its MFMA/LDS
    // with the exp(t) VALU below, filling both pipes in one phase.
    if (it > 0) pv_step(VBh + vprev * 8192);
    __builtin_amdgcn_s_setprio(0);

    // exp(t): p = exp2(s); pack into next iter's PV B-frags.
    s16x8 pkc[2][2];
#pragma unroll
    for (int qg = 0; qg < 2; qg++) {
#pragma unroll
      for (int g = 0; g < 4; g++) {
#pragma unroll
        for (int r = 0; r < 4; r++) {
          float p = __builtin_amdgcn_exp2f(s[g][qg][r]);  // raw v_exp_f32
          pkc[qg][g >> 1][(g & 1) * 4 + r] = (short)bf16_bits(p);
        }
      }
    }
#pragma unroll
    for (int a = 0; a < 2; a++)
#pragma unroll
      for (int b = 0; b < 2; b++) pkp[a][b] = pkc[a][b];   // SSA under unroll

    __builtin_amdgcn_sched_barrier(0);
    __builtin_amdgcn_s_barrier();   // all waves done reading buf[cur]
  }

  // Epilogue: PV for the final tile (V buf (NIT2_-1)%3 untouched since its
  // stage; last loop iter issued no new stage).
  pv_step(VBh + ((NIT2_ - 1) % 3) * 8192);

  // ---- linear merge of the two kv-halves through the (now dead) K/V LDS ---
  float* OS = (float*)KB;          // 32 KB: half-1 o partials (K region dead)
  float* OSS = (float*)VB;         // 2 KB: half-1 denominators (V buf0 dead)
  if (wh == 1) {
    float* dst = OS + t2 * 32;
#pragma unroll
    for (int mt = 0; mt < 4; mt++)
#pragma unroll
      for (int qg = 0; qg < 2; qg++) {
        int c = mt * 2 + qg;   // chunk 0..7, XOR-spread across banks
        *(f32x4*)(dst + ((c ^ (t2 & 7)) * 4)) = o[mt][qg];
      }
    OSS[t2 * 2 + 0] = osum[0][0];
    OSS[t2 * 2 + 1] = osum[1][0];
  }
  __syncthreads();
  if (wh == 0) {
    const float* src = OS + t2 * 32;
    float inv[2] = {1.f / (osum[0][0] + OSS[t2 * 2 + 0]),
                    1.f / (osum[1][0] + OSS[t2 * 2 + 1])};
#pragma unroll
    for (int qg = 0; qg < 2; qg++) {
#pragma unroll
      for (int mt = 0; mt < 4; mt++) {
        int c = mt * 2 + qg;
        f32x4 po = *(const f32x4*)(src + ((c ^ (t2 & 7)) * 4));
        f32x4 ov;
#pragma unroll
        for (int r = 0; r < 4; r++) ov[r] = (o[mt][qg][r] + po[r]) * inv[qg];
        *(ushort4*)(qbase + (size_t)(qg * 16 + lx) * HD_ + mt * 16 + quad * 4)
            = pack4(ov);
      }
    }
  }
}

// ---------------------------------------------------------------------------
// Scratch plan:
//   ws:    q_ws 0-8M | k_ws 8-16M | vt_ws 16-24M | mem_k 24-25M | mem_vt 25-26M
//          | wob 26-28M (only if ws_size >= 28M; else wob aliases k_ws and is
//          converted AFTER attn by the fallback conv kernel)
//   d_out: xb (bf16 x) 0-8M | wqb (bf16 w_qkv) 8-14M   [dead after gemm1;
//          gemm2 overwrites all of d_out with the real output]
// ---------------------------------------------------------------------------
extern "C" void kernel_launch(void* const* d_in, const int* in_sizes, int n_in,
                              void* d_out, int out_size, void* d_ws,
                              size_t ws_size, hipStream_t stream) {
  const float* x      = (const float*)d_in[0];   // [B,T,D]   f32
  const float* w_qkv  = (const float*)d_in[1];   // [3D,D]    f32
  const float* w_out  = (const float*)d_in[2];   // [D,D]     f32
  const float* b_out  = (const float*)d_in[3];   // [D]       f32
  const float* memory = (const float*)d_in[4];   // [MEM,D]   f32

  char* ws = (char*)d_ws;
  bf16* q_ws   = (bf16*)(ws);                    // [32][2048][64]  8 MiB
  bf16* k_ws   = (bf16*)(ws + (8u << 20));       // [32][2048][64]  8 MiB
  bf16* vt_ws  = (bf16*)(ws + (16u << 20));      // [32][64][2048]  8 MiB
  bf16* mem_k  = (bf16*)(ws + (24u << 20));      // [16][512][64]   1 MiB
  bf16* mem_vt = (bf16*)(ws + (25u << 20));      // [1024][512]     1 MiB
  float* out = (float*)d_out;                    // f32 per reference

  char* outc = (char*)d_out;
  bf16* xb  = (bf16*)(outc);                     // 8 MiB scratch in d_out
  bf16* wqb = (bf16*)(outc + (8u << 20));        // 6 MiB scratch in d_out

  const bool big_ws = ws_size >= (28u << 20);
  bf16* wob = big_ws ? (bf16*)(ws + (26u << 20))   // private 2 MiB
                     : (bf16*)(ws + (8u << 20));   // aliases k_ws (post-attn)

  prep<<<dim3(big_ws ? 4608 : 4096), dim3(256), 0, stream>>>(
      x, w_qkv, memory, w_out, xb, wqb, mem_k, mem_vt, wob);
  gemm_bt<0, false, 128><<<dim3(24, 32), dim3(256), 0, stream>>>(
      xb, wqb, nullptr, q_ws, k_ws, vt_ws, nullptr, 1024);
  attn_kernel<<<dim3(512), dim3(512), 0, stream>>>(
      q_ws, k_ws, vt_ws, mem_k, mem_vt);
  if (!big_ws)
    conv_bf16<<<dim3(512), dim3(256), 0, stream>>>(w_out, wob);
  gemm_bt<1, true, 64><<<dim3(16, 32), dim3(256), 0, stream>>>(
      q_ws, wob, b_out, nullptr, nullptr, nullptr, out, 1024);
}

// Round 8
// 248.087 us; speedup vs baseline: 1.0733x; 1.0733x over previous
//
#include <hip/hip_runtime.h>
#include <hip/hip_bf16.h>
#include <stdint.h>

// Problem constants
#define B_   2
#define T_   2048
#define D_   1024
#define H_   16
#define HD_  64
#define MEM_ 512
#define KV_  (MEM_ + T_)   // 2560
#define NIT_ (KV_ / 64)    // 40 kv-tiles of 64
#define NIT2_ (NIT_ / 2)   // 20 per kv-half

using bf16 = __bf16;
typedef __bf16 bf16x8 __attribute__((ext_vector_type(8)));
typedef float  f32x4  __attribute__((ext_vector_type(4)));
typedef short  s16x4  __attribute__((ext_vector_type(4)));
typedef short  s16x8  __attribute__((ext_vector_type(8)));

__device__ __forceinline__ f32x4 mfma16(bf16x8 a, bf16x8 b, f32x4 c) {
  return __builtin_amdgcn_mfma_f32_16x16x32_bf16(a, b, c, 0, 0, 0);
}

// Async global->LDS, 16B per lane (dest = wave-uniform base + lane*16).
__device__ __forceinline__ void gll16(const void* g, void* l) {
  __builtin_amdgcn_global_load_lds(
      (const __attribute__((address_space(1))) unsigned int*)g,
      (__attribute__((address_space(3))) unsigned int*)l, 16, 0, 0);
}

__device__ __forceinline__ unsigned short bf16_bits(float f) {
  bf16 h = (bf16)f;
  return __builtin_bit_cast(unsigned short, h);
}

__device__ __forceinline__ ushort4 pack4(f32x4 v) {
  ushort4 p;
  p.x = bf16_bits(v[0]); p.y = bf16_bits(v[1]);
  p.z = bf16_bits(v[2]); p.w = bf16_bits(v[3]);
  return p;
}

__device__ __forceinline__ bf16x8 cvt8(f32x4 a, f32x4 b) {
  bf16x8 r;
  r[0] = (bf16)a[0]; r[1] = (bf16)a[1]; r[2] = (bf16)a[2]; r[3] = (bf16)a[3];
  r[4] = (bf16)b[0]; r[5] = (bf16)b[1]; r[6] = (bf16)b[2]; r[7] = (bf16)b[3];
  return r;
}

// ---------------------------------------------------------------------------
// prep (fused): blk 0-2047 x conv | 2048-3583 w_qkv conv |
//   3584-3839 memory -> mem_k (row-coalesced) |
//   3840-4095 memory -> mem_vt (column pass, 16B stores) |
//   4096-4607 w_out conv (only when ws has room).
// ---------------------------------------------------------------------------
__global__ void prep(const float* __restrict__ x, const float* __restrict__ wq,
                     const float* __restrict__ memory,
                     const float* __restrict__ wout,
                     bf16* __restrict__ xb, bf16* __restrict__ wqb,
                     bf16* __restrict__ mem_k, bf16* __restrict__ mem_vt,
                     bf16* __restrict__ wob) {
  int blk = blockIdx.x;
  if (blk < 3584) {
    const float* s = (blk < 2048) ? x : wq;
    bf16* d = (blk < 2048) ? xb : wqb;
    size_t i = ((size_t)(blk < 2048 ? blk : blk - 2048) * 256 + threadIdx.x) * 8;
    f32x4 a = *(const f32x4*)(s + i);
    f32x4 b = *(const f32x4*)(s + i + 4);
    *(bf16x8*)(d + i) = cvt8(a, b);
  } else if (blk < 3840) {
    int idx8 = ((blk - 3584) * 256 + threadIdx.x) * 8;   // [0, 512*1024)
    int m = idx8 >> 10, d0 = idx8 & 1023;
    int hh = d0 >> 6, hd0 = d0 & 63;
    f32x4 a = *(const f32x4*)(memory + idx8);
    f32x4 b = *(const f32x4*)(memory + idx8 + 4);
    *(bf16x8*)&mem_k[((size_t)hh * MEM_ + m) * HD_ + hd0] = cvt8(a, b);
  } else if (blk < 4096) {
    int idx = (blk - 3840) * 256 + threadIdx.x;          // [0, 65536)
    int d = idx & 1023;
    int m0 = (idx >> 10) * 8;                            // 0..511 step 8
    bf16x8 r;
#pragma unroll
    for (int j = 0; j < 8; j++)
      r[j] = (bf16)memory[(size_t)(m0 + j) * D_ + d];
    *(bf16x8*)&mem_vt[(size_t)d * MEM_ + m0] = r;
  } else {
    size_t i = ((size_t)(blk - 4096) * 256 + threadIdx.x) * 8;
    f32x4 a = *(const f32x4*)(wout + i);
    f32x4 b = *(const f32x4*)(wout + i + 4);
    *(bf16x8*)(wob + i) = cvt8(a, b);
  }
}

// w_out conv fallback: runs AFTER attn (dest aliases k_ws, dead by then).
__global__ void conv_bf16(const float* __restrict__ s, bf16* __restrict__ d) {
  size_t i = ((size_t)blockIdx.x * 256 + threadIdx.x) * 8;
  f32x4 a = *(const f32x4*)(s + i);
  f32x4 b = *(const f32x4*)(s + i + 4);
  *(bf16x8*)(d + i) = cvt8(a, b);
}

// ---------------------------------------------------------------------------
// GEMM (B^T form): C[M,N] = A[M,K] * W[N,K]^T.  128 x NTILE tile, BK=64
// (32 MFMA per barrier pair), 4 waves (2x2).  global_load_lds w16 staging,
// 16B-chunk XOR swizzle both-sides, bijective XCD swizzle (T1).
// EPI==0: scatter q/k -> [bh][t][64], v -> vt_ws[bh][hd][t] (transposed).
// EPI==1: bias add -> Cout [M][1024] f32.  APLANE: A is plane layout.
// ---------------------------------------------------------------------------
template <int EPI, bool APLANE, int NTILE>
__global__ __launch_bounds__(256, 3) void gemm_bt(
    const bf16* __restrict__ A, const bf16* __restrict__ W,
    const float* __restrict__ bias,
    bf16* __restrict__ q_ws, bf16* __restrict__ k_ws, bf16* __restrict__ vt_ws,
    float* __restrict__ Cout, int K) {
  constexpr int NF = NTILE / 32;        // n-frags per wave
  constexpr int NB = NTILE / 32;        // B-tile gll count
  __shared__ __align__(16) bf16 Als[128 * 64];
  __shared__ __align__(16) bf16 Bls[NTILE * 64];
  char* AB = (char*)Als;
  char* BB = (char*)Bls;
  // Bijective XCD swizzle (nwg % 8 == 0 for both launches).
  const int nwg = gridDim.x * gridDim.y;
  int lin = blockIdx.y * gridDim.x + blockIdx.x;
  lin = (lin & 7) * (nwg >> 3) + (lin >> 3);
  const int m0 = (lin / gridDim.x) * 128;
  const int n0 = (lin % gridDim.x) * NTILE;
  const int tid = threadIdx.x;
  const int w = tid >> 6;
  const int lane = tid & 63;
  const int lx = lane & 15;
  const int quad = lane >> 4;
  const int amb = (w & 1) * 64;
  const int bnb = (w >> 1) * (NTILE / 2);
  const int srow = tid >> 3;                        // 0..31 (+32g per gll)
  const int cs = (tid & 7) ^ (srow & 7);            // swizzled source chunk

  f32x4 acc[4][NF];
#pragma unroll
  for (int i = 0; i < 4; i++)
#pragma unroll
    for (int j = 0; j < NF; j++) acc[i][j] = (f32x4){0.f, 0.f, 0.f, 0.f};

  for (int k0 = 0; k0 < K; k0 += 64) {
    const bf16* pa[4];
#pragma unroll
    for (int g = 0; g < 4; g++) {
      int r = srow + 32 * g;
      if constexpr (APLANE) {
        int hh = k0 >> 6, hd = cs * 8;
        int mA = m0 + r;
        pa[g] = A + ((size_t)((mA >> 11) * H_ + hh) * T_ + (mA & 2047)) * HD_ + hd;
      } else {
        pa[g] = A + (size_t)(m0 + r) * K + k0 + cs * 8;
      }
    }
    const bf16* pb[NB];
#pragma unroll
    for (int g = 0; g < NB; g++)
      pb[g] = W + (size_t)(n0 + srow + 32 * g) * K + k0 + cs * 8;

    __syncthreads();   // prev iteration's LDS reads done
#pragma unroll
    for (int g = 0; g < 4; g++) gll16(pa[g], AB + g * 4096 + tid * 16);
#pragma unroll
    for (int g = 0; g < NB; g++) gll16(pb[g], BB + g * 4096 + tid * 16);
    __syncthreads();   // drains vmcnt -> tiles valid

    bf16x8 af[4][2], bfr[NF][2];
    const int rk = (lx & 7) << 4;   // read-side swizzle key (row&7 == lx&7)
#pragma unroll
    for (int mt = 0; mt < 4; mt++)
#pragma unroll
      for (int kh = 0; kh < 2; kh++)
        af[mt][kh] = *(const bf16x8*)(AB + (size_t)(amb + mt * 16 + lx) * 128 +
                                      ((quad * 16 + kh * 64) ^ rk));
#pragma unroll
    for (int nt = 0; nt < NF; nt++)
#pragma unroll
      for (int kh = 0; kh < 2; kh++)
        bfr[nt][kh] = *(const bf16x8*)(BB + (size_t)(bnb + nt * 16 + lx) * 128 +
                                       ((quad * 16 + kh * 64) ^ rk));
#pragma unroll
    for (int kh = 0; kh < 2; kh++)
#pragma unroll
      for (int mt = 0; mt < 4; mt++)
#pragma unroll
        for (int nt = 0; nt < NF; nt++)
          acc[mt][nt] = mfma16(af[mt][kh], bfr[nt][kh], acc[mt][nt]);
  }

  // Epilogue. C/D layout: row = quad*4+reg (m), col = lane&15 (n).
  if (EPI == 0) {
#pragma unroll
    for (int mt = 0; mt < 4; mt++) {
      int mbase = m0 + amb + mt * 16 + quad * 4;
      int b = mbase >> 11;        // T=2048
      int t = mbase & 2047;
#pragma unroll
      for (int nt = 0; nt < NF; nt++) {
        int col = n0 + bnb + nt * 16 + lx;     // [0,3072)
        int which = col >> 10;                 // 0=q 1=k 2=v
        int d = col & 1023;
        int hh = d >> 6, hdi = d & 63;
        int bh = b * H_ + hh;
        if (which == 0) {
#pragma unroll
          for (int r = 0; r < 4; r++)
            q_ws[((size_t)bh * T_ + t + r) * HD_ + hdi] = (bf16)acc[mt][nt][r];
        } else if (which == 1) {
#pragma unroll
          for (int r = 0; r < 4; r++)
            k_ws[((size_t)bh * T_ + t + r) * HD_ + hdi] = (bf16)acc[mt][nt][r];
        } else {
          // v^T: 4 consecutive t -> one 8B store
          *(ushort4*)&vt_ws[((size_t)bh * HD_ + hdi) * T_ + t] =
              pack4(acc[mt][nt]);
        }
      }
    }
  } else {
#pragma unroll
    for (int nt = 0; nt < NF; nt++) {
      int col = n0 + bnb + nt * 16 + lx;
      float bias_f = bias[col];
#pragma unroll
      for (int mt = 0; mt < 4; mt++) {
        int mbase = m0 + amb + mt * 16 + quad * 4;
#pragma unroll
        for (int r = 0; r < 4; r++)
          Cout[(size_t)(mbase + r) * D_ + col] = acc[mt][nt][r] + bias_f;
      }
    }
  }
}

// ---------------------------------------------------------------------------
// Flash attention, kv-split x2 + deferred-PV pipeline, SINGLE-P-BUFFER:
// iteration t: QK(t) -> PV(t-1) [consumes pkp] -> exp(t) [overwrites pkp].
// Register pressure stays near R6 (one 16-VGPR pk array; only `s` spans PV).
// R7's spill (FETCH 190MB / WRITE 290MB of scratch) came from the full
// 20x unroll + double P-buffer; this keeps the loop ROLLED (unroll 2 for
// static K-buffer parity) and one P array.  V triple-buffered in LDS so
// stage(t+1) never overwrites V(t-1); K double-buffered; 80 KB -> 2 blk/CU.
// PV skipped at it=0; last PV runs as epilogue.  Ones-MFMA row-sum,
// full-rate k32 PV (contraction relabel).  Linear kv-half merge via LDS.
// 1 block = 128 q of one (b,h); grid 512; output in q_ws.
// ---------------------------------------------------------------------------
__global__ __launch_bounds__(512, 4) void attn_kernel(
    bf16* __restrict__ q_ws, const bf16* __restrict__ k_ws,
    const bf16* __restrict__ vt_ws, const bf16* __restrict__ mem_k,
    const bf16* __restrict__ mem_vt) {
  __shared__ __align__(16) bf16 Kls[2 * 2 * 64 * 64];   // [half][kbuf] 32 KB
  __shared__ __align__(16) bf16 Vls[2 * 3 * 64 * 64];   // [half][vbuf] 48 KB
  char* KB = (char*)Kls;
  char* VB = (char*)Vls;
  const int tid = threadIdx.x;         // 0..511
  const int wh = tid >> 8;             // kv-half
  const int t2 = tid & 255;
  const int w = t2 >> 6;               // wave within half
  const int lane = tid & 63;
  const int lx = lane & 15;
  const int quad = lane >> 4;
  const int bh = blockIdx.x & 31;      // XCD-locality
  const int qt = blockIdx.x >> 5;      // 16 q-tiles of 128
  const int q0 = qt * 128 + w * 32;
  const int h = bh & 15;

  const int srow1 = t2 >> 3;               // 0..31
  const int sc1 = (t2 & 7) ^ (srow1 & 7);  // pre-swizzled source chunk

  char* KBh = KB + wh * 16384;   // 2 bufs x 8 KB
  char* VBh = VB + wh * 24576;   // 3 bufs x 8 KB

  bf16* qbase = q_ws + ((size_t)bh * T_ + q0) * HD_;

  const bf16* kpl = k_ws + (size_t)bh * T_ * HD_;
  const bf16* vpl = vt_ws + (size_t)bh * HD_ * T_;
  const bf16* mkp = mem_k + (size_t)h * MEM_ * HD_;   // per-head plane
  const bf16* mvp = mem_vt + (size_t)h * HD_ * MEM_;

  // Stage this half's kv-tile `it2` into K buf kbi / V buf vbi.
  auto stage = [&](int it2, int kbi, int vbi) {
    const int kv0 = (wh * NIT2_ + it2) * 64;
    const bf16 *kp1, *kp2, *vp1, *vp2;
    if (kv0 < MEM_) {
      kp1 = mkp + (size_t)(kv0 + srow1) * HD_ + sc1 * 8;
      kp2 = kp1 + (size_t)32 * HD_;
      vp1 = mvp + (size_t)srow1 * MEM_ + kv0 + sc1 * 8;
      vp2 = vp1 + (size_t)32 * MEM_;
    } else {
      const int t0 = kv0 - MEM_;
      kp1 = kpl + (size_t)(t0 + srow1) * HD_ + sc1 * 8;
      kp2 = kp1 + (size_t)32 * HD_;
      vp1 = vpl + (size_t)srow1 * T_ + t0 + sc1 * 8;
      vp2 = vp1 + (size_t)32 * T_;
    }
    char* kb = KBh + kbi * 8192;
    char* vb = VBh + vbi * 8192;
    gll16(kp1, kb + t2 * 16);
    gll16(kp2, kb + t2 * 16 + 4096);
    gll16(vp1, vb + t2 * 16);
    gll16(vp2, vb + t2 * 16 + 4096);
  };

  // Q B-frags (k32); fold softmax scale AND log2(e) into Q:
  // s = (q*0.125*log2e) . k  ->  exp2(s) == exp(0.125 * q.k)
  const float QSCALE = 0.125f * 1.44269504089f;
  bf16x8 qf[2][2];
#pragma unroll
  for (int qg = 0; qg < 2; qg++)
#pragma unroll
    for (int hf = 0; hf < 2; hf++) {
      bf16x8 v = *(const bf16x8*)(qbase + (size_t)(qg * 16 + lx) * HD_ +
                                  hf * 32 + quad * 8);
#pragma unroll
      for (int i = 0; i < 8; i++)
        v[i] = (bf16)((float)v[i] * QSCALE);
      qf[qg][hf] = v;
    }

  bf16x8 ones;
#pragma unroll
  for (int i = 0; i < 8; i++) ones[i] = (bf16)1.0f;

  f32x4 o[4][2];
#pragma unroll
  for (int mt = 0; mt < 4; mt++)
#pragma unroll
    for (int qg = 0; qg < 2; qg++) o[mt][qg] = (f32x4){0.f, 0.f, 0.f, 0.f};
  f32x4 osum[2] = {(f32x4){0.f, 0.f, 0.f, 0.f}, (f32x4){0.f, 0.f, 0.f, 0.f}};

  s16x8 pkp[2][2];   // the ONLY P storage (prev tile); 16 VGPRs
  const int sw = (lx & 7) << 4;   // read-side swizzle (row&7 == lx&7)

  // PV for the PREVIOUS tile from V buffer VBp using pkp.
  auto pv_step = [&](const char* VBp) {
#pragma unroll
    for (int mt = 0; mt < 4; mt++) {
      const char* vb = VBp + (size_t)(mt * 16 + lx) * 128;
#pragma unroll
      for (int p = 0; p < 2; p++) {
        // A-frag: V[d][kv] at kv-chunks p*32+quad*4 and p*32+16+quad*4
        s16x4 lo = *(const s16x4*)(vb + ((p * 64 + quad * 8) ^ sw));
        s16x4 hi = *(const s16x4*)(vb + ((p * 64 + 32 + quad * 8) ^ sw));
        s16x8 cat = __builtin_shufflevector(lo, hi, 0, 1, 2, 3, 4, 5, 6, 7);
        bf16x8 va = __builtin_bit_cast(bf16x8, cat);
#pragma unroll
        for (int qg = 0; qg < 2; qg++)
          o[mt][qg] = mfma16(va, __builtin_bit_cast(bf16x8, pkp[qg][p]),
                             o[mt][qg]);
      }
    }
    // denominator: osum[qg] += 1^T . P  (all C rows identical)
#pragma unroll
    for (int p = 0; p < 2; p++)
#pragma unroll
      for (int qg = 0; qg < 2; qg++)
        osum[qg] = mfma16(ones, __builtin_bit_cast(bf16x8, pkp[qg][p]),
                          osum[qg]);
  };

  stage(0, 0, 0);   // prologue prefetch

#pragma unroll 2
  for (int it = 0; it < NIT2_; it++) {
    const int kc = it & 1;
    const int vprev = (it + 2) % 3;          // == (it-1) % 3
    if (it + 1 < NIT2_) {
      stage(it + 1, kc ^ 1, (it + 1) % 3);
      asm volatile("s_waitcnt vmcnt(4)" ::: "memory");   // cur's 4 loads done
    } else {
      asm volatile("s_waitcnt vmcnt(0)" ::: "memory");
    }
    __builtin_amdgcn_s_barrier();        // all waves' cur parts landed
    __builtin_amdgcn_sched_barrier(0);

    const char* KBc = KBh + kc * 8192;
    f32x4 s[4][2];
    __builtin_amdgcn_s_setprio(1);
    // QK(t)
#pragma unroll
    for (int g = 0; g < 4; g++) {
      const char* kb = KBc + (size_t)(g * 16 + lx) * 128;
      bf16x8 ka0 = *(const bf16x8*)(kb + ((quad * 16) ^ sw));
      bf16x8 ka1 = *(const bf16x8*)(kb + ((64 + quad * 16) ^ sw));
#pragma unroll
      for (int qg = 0; qg < 2; qg++) {
        s[g][qg] = (f32x4){0.f, 0.f, 0.f, 0.f};
        s[g][qg] = mfma16(ka0, qf[qg][0], s[g][qg]);
        s[g][qg] = mfma16(ka1, qf[qg][1], s[g][qg]);
      }
    }
    // PV(t-1): independent of s(t); consumes pkp, freeing it for exp(t).
    // Its MFMA/LDS interleaves with the exp(t) VALU below in one phase.
    if (it > 0) pv_step(VBh + vprev * 8192);
    __builtin_amdgcn_s_setprio(0);

    // exp(t): p = exp2(s); overwrite pkp (PV above already consumed it).
#pragma unroll
    for (int qg = 0; qg < 2; qg++) {
#pragma unroll
      for (int g = 0; g < 4; g++) {
#pragma unroll
        for (int r = 0; r < 4; r++) {
          float p = __builtin_amdgcn_exp2f(s[g][qg][r]);  // raw v_exp_f32
          pkp[qg][g >> 1][(g & 1) * 4 + r] = (short)bf16_bits(p);
        }
      }
    }

    __builtin_amdgcn_sched_barrier(0);
    __builtin_amdgcn_s_barrier();   // all waves done reading buf[cur]
  }

  // Epilogue: PV for the final tile (its V buf untouched since staging).
  pv_step(VBh + ((NIT2_ - 1) % 3) * 8192);

  // ---- linear merge of the two kv-halves through the (now dead) K/V LDS ---
  float* OS = (float*)KB;          // 32 KB: half-1 o partials (K region dead)
  float* OSS = (float*)VB;         // 2 KB: half-1 denominators (V buf0 dead)
  if (wh == 1) {
    float* dst = OS + t2 * 32;
#pragma unroll
    for (int mt = 0; mt < 4; mt++)
#pragma unroll
      for (int qg = 0; qg < 2; qg++) {
        int c = mt * 2 + qg;   // chunk 0..7, XOR-spread across banks
        *(f32x4*)(dst + ((c ^ (t2 & 7)) * 4)) = o[mt][qg];
      }
    OSS[t2 * 2 + 0] = osum[0][0];
    OSS[t2 * 2 + 1] = osum[1][0];
  }
  __syncthreads();
  if (wh == 0) {
    const float* src = OS + t2 * 32;
    float inv[2] = {1.f / (osum[0][0] + OSS[t2 * 2 + 0]),
                    1.f / (osum[1][0] + OSS[t2 * 2 + 1])};
#pragma unroll
    for (int qg = 0; qg < 2; qg++) {
#pragma unroll
      for (int mt = 0; mt < 4; mt++) {
        int c = mt * 2 + qg;
        f32x4 po = *(const f32x4*)(src + ((c ^ (t2 & 7)) * 4));
        f32x4 ov;
#pragma unroll
        for (int r = 0; r < 4; r++) ov[r] = (o[mt][qg][r] + po[r]) * inv[qg];
        *(ushort4*)(qbase + (size_t)(qg * 16 + lx) * HD_ + mt * 16 + quad * 4)
            = pack4(ov);
      }
    }
  }
}

// ---------------------------------------------------------------------------
// Scratch plan:
//   ws:    q_ws 0-8M | k_ws 8-16M | vt_ws 16-24M | mem_k 24-25M | mem_vt 25-26M
//          | wob 26-28M (only if ws_size >= 28M; else wob aliases k_ws and is
//          converted AFTER attn by the fallback conv kernel)
//   d_out: xb (bf16 x) 0-8M | wqb (bf16 w_qkv) 8-14M   [dead after gemm1;
//          gemm2 overwrites all of d_out with the real output]
// ---------------------------------------------------------------------------
extern "C" void kernel_launch(void* const* d_in, const int* in_sizes, int n_in,
                              void* d_out, int out_size, void* d_ws,
                              size_t ws_size, hipStream_t stream) {
  const float* x      = (const float*)d_in[0];   // [B,T,D]   f32
  const float* w_qkv  = (const float*)d_in[1];   // [3D,D]    f32
  const float* w_out  = (const float*)d_in[2];   // [D,D]     f32
  const float* b_out  = (const float*)d_in[3];   // [D]       f32
  const float* memory = (const float*)d_in[4];   // [MEM,D]   f32

  char* ws = (char*)d_ws;
  bf16* q_ws   = (bf16*)(ws);                    // [32][2048][64]  8 MiB
  bf16* k_ws   = (bf16*)(ws + (8u << 20));       // [32][2048][64]  8 MiB
  bf16* vt_ws  = (bf16*)(ws + (16u << 20));      // [32][64][2048]  8 MiB
  bf16* mem_k  = (bf16*)(ws + (24u << 20));      // [16][512][64]   1 MiB
  bf16* mem_vt = (bf16*)(ws + (25u << 20));      // [1024][512]     1 MiB
  float* out = (float*)d_out;                    // f32 per reference

  char* outc = (char*)d_out;
  bf16* xb  = (bf16*)(outc);                     // 8 MiB scratch in d_out
  bf16* wqb = (bf16*)(outc + (8u << 20));        // 6 MiB scratch in d_out

  const bool big_ws = ws_size >= (28u << 20);
  bf16* wob = big_ws ? (bf16*)(ws + (26u << 20))   // private 2 MiB
                     : (bf16*)(ws + (8u << 20));   // aliases k_ws (post-attn)

  prep<<<dim3(big_ws ? 4608 : 4096), dim3(256), 0, stream>>>(
      x, w_qkv, memory, w_out, xb, wqb, mem_k, mem_vt, wob);
  gemm_bt<0, false, 128><<<dim3(24, 32), dim3(256), 0, stream>>>(
      xb, wqb, nullptr, q_ws, k_ws, vt_ws, nullptr, 1024);
  attn_kernel<<<dim3(512), dim3(512), 0, stream>>>(
      q_ws, k_ws, vt_ws, mem_k, mem_vt);
  if (!big_ws)
    conv_bf16<<<dim3(512), dim3(256), 0, stream>>>(w_out, wob);
  gemm_bt<1, true, 64><<<dim3(16, 32), dim3(256), 0, stream>>>(
      q_ws, wob, b_out, nullptr, nullptr, nullptr, out, 1024);
}

// Round 9
// 180.771 us; speedup vs baseline: 1.4730x; 1.3724x over previous
//
#include <hip/hip_runtime.h>
#include <hip/hip_bf16.h>
#include <stdint.h>

// Problem constants
#define B_   2
#define T_   2048
#define D_   1024
#define H_   16
#define HD_  64
#define MEM_ 512
#define KV_  (MEM_ + T_)   // 2560
#define NIT_ (KV_ / 64)    // 40 kv-tiles of 64
#define NIT2_ (NIT_ / 2)   // 20 per kv-half

using bf16 = __bf16;
typedef __bf16 bf16x8 __attribute__((ext_vector_type(8)));
typedef float  f32x4  __attribute__((ext_vector_type(4)));
typedef short  s16x4  __attribute__((ext_vector_type(4)));
typedef short  s16x8  __attribute__((ext_vector_type(8)));

__device__ __forceinline__ f32x4 mfma16(bf16x8 a, bf16x8 b, f32x4 c) {
  return __builtin_amdgcn_mfma_f32_16x16x32_bf16(a, b, c, 0, 0, 0);
}

// Async global->LDS, 16B per lane (dest = wave-uniform base + lane*16).
__device__ __forceinline__ void gll16(const void* g, void* l) {
  __builtin_amdgcn_global_load_lds(
      (const __attribute__((address_space(1))) unsigned int*)g,
      (__attribute__((address_space(3))) unsigned int*)l, 16, 0, 0);
}

__device__ __forceinline__ unsigned short bf16_bits(float f) {
  bf16 h = (bf16)f;
  return __builtin_bit_cast(unsigned short, h);
}

__device__ __forceinline__ ushort4 pack4(f32x4 v) {
  ushort4 p;
  p.x = bf16_bits(v[0]); p.y = bf16_bits(v[1]);
  p.z = bf16_bits(v[2]); p.w = bf16_bits(v[3]);
  return p;
}

__device__ __forceinline__ bf16x8 cvt8(f32x4 a, f32x4 b) {
  bf16x8 r;
  r[0] = (bf16)a[0]; r[1] = (bf16)a[1]; r[2] = (bf16)a[2]; r[3] = (bf16)a[3];
  r[4] = (bf16)b[0]; r[5] = (bf16)b[1]; r[6] = (bf16)b[2]; r[7] = (bf16)b[3];
  return r;
}

// V^T kv-column permutation within each 64-aligned tile: u = 16g+4c+r
// stored at pos = (g>>1)*32 + c*8 + (g&1)*4 + r.  Makes PV's two 4-elem
// pieces (kv p*32+4q and p*32+16+4q) ADJACENT 16B in LDS -> single b128
// read at (p*64+quad*16)^sw, same conflict-free pattern as the K reads.
__device__ __forceinline__ int vperm4(int u) {   // u multiple of 4
  int g = u >> 4, c = (u >> 2) & 3;
  return (g >> 1) * 32 + c * 8 + (g & 1) * 4;
}

// ---------------------------------------------------------------------------
// prep (fused): blk 0-2047 x conv | 2048-3583 w_qkv conv |
//   3584-3839 memory -> mem_k (row-coalesced) |
//   3840-4095 memory -> mem_vt (column pass; 2x8B permuted stores) |
//   4096-4607 w_out conv (only when ws has room).
// ---------------------------------------------------------------------------
__global__ void prep(const float* __restrict__ x, const float* __restrict__ wq,
                     const float* __restrict__ memory,
                     const float* __restrict__ wout,
                     bf16* __restrict__ xb, bf16* __restrict__ wqb,
                     bf16* __restrict__ mem_k, bf16* __restrict__ mem_vt,
                     bf16* __restrict__ wob) {
  int blk = blockIdx.x;
  if (blk < 3584) {
    const float* s = (blk < 2048) ? x : wq;
    bf16* d = (blk < 2048) ? xb : wqb;
    size_t i = ((size_t)(blk < 2048 ? blk : blk - 2048) * 256 + threadIdx.x) * 8;
    f32x4 a = *(const f32x4*)(s + i);
    f32x4 b = *(const f32x4*)(s + i + 4);
    *(bf16x8*)(d + i) = cvt8(a, b);
  } else if (blk < 3840) {
    int idx8 = ((blk - 3584) * 256 + threadIdx.x) * 8;   // [0, 512*1024)
    int m = idx8 >> 10, d0 = idx8 & 1023;
    int hh = d0 >> 6, hd0 = d0 & 63;
    f32x4 a = *(const f32x4*)(memory + idx8);
    f32x4 b = *(const f32x4*)(memory + idx8 + 4);
    *(bf16x8*)&mem_k[((size_t)hh * MEM_ + m) * HD_ + hd0] = cvt8(a, b);
  } else if (blk < 4096) {
    int idx = (blk - 3840) * 256 + threadIdx.x;          // [0, 65536)
    int d = idx & 1023;
    int m0 = (idx >> 10) * 8;                            // 0..511 step 8
    bf16x8 r;
#pragma unroll
    for (int j = 0; j < 8; j++)
      r[j] = (bf16)memory[(size_t)(m0 + j) * D_ + d];
    // permuted store: groups (g,c) and (g,c+1) land at pos and pos+8
    int u = m0 & 63;
    bf16* dst = &mem_vt[(size_t)d * MEM_ + (m0 - u) + vperm4(u)];
    s16x8 rb = __builtin_bit_cast(s16x8, r);
    *(s16x4*)dst = __builtin_shufflevector(rb, rb, 0, 1, 2, 3);
    *(s16x4*)(dst + 8) = __builtin_shufflevector(rb, rb, 4, 5, 6, 7);
  } else {
    size_t i = ((size_t)(blk - 4096) * 256 + threadIdx.x) * 8;
    f32x4 a = *(const f32x4*)(wout + i);
    f32x4 b = *(const f32x4*)(wout + i + 4);
    *(bf16x8*)(wob + i) = cvt8(a, b);
  }
}

// w_out conv fallback: runs AFTER attn (dest aliases k_ws, dead by then).
__global__ void conv_bf16(const float* __restrict__ s, bf16* __restrict__ d) {
  size_t i = ((size_t)blockIdx.x * 256 + threadIdx.x) * 8;
  f32x4 a = *(const f32x4*)(s + i);
  f32x4 b = *(const f32x4*)(s + i + 4);
  *(bf16x8*)(d + i) = cvt8(a, b);
}

// ---------------------------------------------------------------------------
// GEMM (B^T form): C[M,N] = A[M,K] * W[N,K]^T.  128 x NTILE tile, BK=64
// (32 MFMA per barrier pair), 4 waves (2x2).  global_load_lds w16 staging,
// 16B-chunk XOR swizzle both-sides, bijective XCD swizzle (T1).
// EPI==0: scatter q/k -> [bh][t][64], v -> vt_ws[bh][hd][t] with the vperm4
//         kv-column permutation (see above).
// EPI==1: bias add -> Cout [M][1024] f32.  APLANE: A is plane layout.
// ---------------------------------------------------------------------------
template <int EPI, bool APLANE, int NTILE>
__global__ __launch_bounds__(256, 3) void gemm_bt(
    const bf16* __restrict__ A, const bf16* __restrict__ W,
    const float* __restrict__ bias,
    bf16* __restrict__ q_ws, bf16* __restrict__ k_ws, bf16* __restrict__ vt_ws,
    float* __restrict__ Cout, int K) {
  constexpr int NF = NTILE / 32;        // n-frags per wave
  constexpr int NB = NTILE / 32;        // B-tile gll count
  __shared__ __align__(16) bf16 Als[128 * 64];
  __shared__ __align__(16) bf16 Bls[NTILE * 64];
  char* AB = (char*)Als;
  char* BB = (char*)Bls;
  // Bijective XCD swizzle (nwg % 8 == 0 for both launches).
  const int nwg = gridDim.x * gridDim.y;
  int lin = blockIdx.y * gridDim.x + blockIdx.x;
  lin = (lin & 7) * (nwg >> 3) + (lin >> 3);
  const int m0 = (lin / gridDim.x) * 128;
  const int n0 = (lin % gridDim.x) * NTILE;
  const int tid = threadIdx.x;
  const int w = tid >> 6;
  const int lane = tid & 63;
  const int lx = lane & 15;
  const int quad = lane >> 4;
  const int amb = (w & 1) * 64;
  const int bnb = (w >> 1) * (NTILE / 2);
  const int srow = tid >> 3;                        // 0..31 (+32g per gll)
  const int cs = (tid & 7) ^ (srow & 7);            // swizzled source chunk

  f32x4 acc[4][NF];
#pragma unroll
  for (int i = 0; i < 4; i++)
#pragma unroll
    for (int j = 0; j < NF; j++) acc[i][j] = (f32x4){0.f, 0.f, 0.f, 0.f};

  for (int k0 = 0; k0 < K; k0 += 64) {
    const bf16* pa[4];
#pragma unroll
    for (int g = 0; g < 4; g++) {
      int r = srow + 32 * g;
      if constexpr (APLANE) {
        int hh = k0 >> 6, hd = cs * 8;
        int mA = m0 + r;
        pa[g] = A + ((size_t)((mA >> 11) * H_ + hh) * T_ + (mA & 2047)) * HD_ + hd;
      } else {
        pa[g] = A + (size_t)(m0 + r) * K + k0 + cs * 8;
      }
    }
    const bf16* pb[NB];
#pragma unroll
    for (int g = 0; g < NB; g++)
      pb[g] = W + (size_t)(n0 + srow + 32 * g) * K + k0 + cs * 8;

    __syncthreads();   // prev iteration's LDS reads done
#pragma unroll
    for (int g = 0; g < 4; g++) gll16(pa[g], AB + g * 4096 + tid * 16);
#pragma unroll
    for (int g = 0; g < NB; g++) gll16(pb[g], BB + g * 4096 + tid * 16);
    __syncthreads();   // drains vmcnt -> tiles valid

    bf16x8 af[4][2], bfr[NF][2];
    const int rk = (lx & 7) << 4;   // read-side swizzle key (row&7 == lx&7)
#pragma unroll
    for (int mt = 0; mt < 4; mt++)
#pragma unroll
      for (int kh = 0; kh < 2; kh++)
        af[mt][kh] = *(const bf16x8*)(AB + (size_t)(amb + mt * 16 + lx) * 128 +
                                      ((quad * 16 + kh * 64) ^ rk));
#pragma unroll
    for (int nt = 0; nt < NF; nt++)
#pragma unroll
      for (int kh = 0; kh < 2; kh++)
        bfr[nt][kh] = *(const bf16x8*)(BB + (size_t)(bnb + nt * 16 + lx) * 128 +
                                       ((quad * 16 + kh * 64) ^ rk));
#pragma unroll
    for (int kh = 0; kh < 2; kh++)
#pragma unroll
      for (int mt = 0; mt < 4; mt++)
#pragma unroll
        for (int nt = 0; nt < NF; nt++)
          acc[mt][nt] = mfma16(af[mt][kh], bfr[nt][kh], acc[mt][nt]);
  }

  // Epilogue. C/D layout: row = quad*4+reg (m), col = lane&15 (n).
  if (EPI == 0) {
#pragma unroll
    for (int mt = 0; mt < 4; mt++) {
      int mbase = m0 + amb + mt * 16 + quad * 4;
      int b = mbase >> 11;        // T=2048
      int t = mbase & 2047;
#pragma unroll
      for (int nt = 0; nt < NF; nt++) {
        int col = n0 + bnb + nt * 16 + lx;     // [0,3072)
        int which = col >> 10;                 // 0=q 1=k 2=v
        int d = col & 1023;
        int hh = d >> 6, hdi = d & 63;
        int bh = b * H_ + hh;
        if (which == 0) {
#pragma unroll
          for (int r = 0; r < 4; r++)
            q_ws[((size_t)bh * T_ + t + r) * HD_ + hdi] = (bf16)acc[mt][nt][r];
        } else if (which == 1) {
#pragma unroll
          for (int r = 0; r < 4; r++)
            k_ws[((size_t)bh * T_ + t + r) * HD_ + hdi] = (bf16)acc[mt][nt][r];
        } else {
          // v^T: 4 consecutive t -> one 8B store at the PERMUTED column
          int u = t & 63;
          *(ushort4*)&vt_ws[((size_t)bh * HD_ + hdi) * T_ + (t - u) +
                            vperm4(u)] = pack4(acc[mt][nt]);
        }
      }
    }
  } else {
#pragma unroll
    for (int nt = 0; nt < NF; nt++) {
      int col = n0 + bnb + nt * 16 + lx;
      float bias_f = bias[col];
#pragma unroll
      for (int mt = 0; mt < 4; mt++) {
        int mbase = m0 + amb + mt * 16 + quad * 4;
#pragma unroll
        for (int r = 0; r < 4; r++)
          Cout[(size_t)(mbase + r) * D_ + col] = acc[mt][nt][r] + bias_f;
      }
    }
  }
}

// ---------------------------------------------------------------------------
// Flash attention (R6 structure — proven 56.9 us — plus b128 PV reads):
// 512 threads = 2 kv-halves x 4 waves, kv-split x2, double-buffered LDS per
// half, counted vmcnt, raw s_barrier.  PV at full-rate k32; thanks to the
// vperm4 column permutation the A-frag is ONE b128 read at
// (p*64+quad*16)^sw — identical conflict-free pattern to the K reads
// (replaces 4x b64 with 2x b128 per mt, kills the V-side bank conflicts).
// Ones-MFMA row-sum for the denominator; linear kv-half merge via LDS.
// NOTE (R7/R8 lesson): nothing bulky may live across the tile barrier
// except o/osum — deferred-PV spills to scratch at this occupancy.
// 1 block = 128 q of one (b,h); grid 512; output in q_ws.
// ---------------------------------------------------------------------------
__global__ __launch_bounds__(512, 4) void attn_kernel(
    bf16* __restrict__ q_ws, const bf16* __restrict__ k_ws,
    const bf16* __restrict__ vt_ws, const bf16* __restrict__ mem_k,
    const bf16* __restrict__ mem_vt) {
  __shared__ __align__(16) bf16 Kls[2 * 2 * 64 * 64];   // [half][buf] 32 KB
  __shared__ __align__(16) bf16 Vls[2 * 2 * 64 * 64];   // [half][buf] 32 KB
  char* KB = (char*)Kls;
  char* VB = (char*)Vls;
  const int tid = threadIdx.x;         // 0..511
  const int wh = tid >> 8;             // kv-half
  const int t2 = tid & 255;
  const int w = t2 >> 6;               // wave within half
  const int lane = tid & 63;
  const int lx = lane & 15;
  const int quad = lane >> 4;
  const int bh = blockIdx.x & 31;      // XCD-locality
  const int qt = blockIdx.x >> 5;      // 16 q-tiles of 128
  const int q0 = qt * 128 + w * 32;
  const int h = bh & 15;

  const int srow1 = t2 >> 3;               // 0..31
  const int sc1 = (t2 & 7) ^ (srow1 & 7);  // pre-swizzled source chunk

  char* KBh = KB + wh * 16384;
  char* VBh = VB + wh * 16384;

  bf16* qbase = q_ws + ((size_t)bh * T_ + q0) * HD_;

  const bf16* kpl = k_ws + (size_t)bh * T_ * HD_;
  const bf16* vpl = vt_ws + (size_t)bh * HD_ * T_;
  const bf16* mkp = mem_k + (size_t)h * MEM_ * HD_;   // per-head plane
  const bf16* mvp = mem_vt + (size_t)h * HD_ * MEM_;

  // Stage this half's kv-tile `it2` (local index) into buffer `bi`.
  auto stage = [&](int it2, int bi) {
    const int kv0 = (wh * NIT2_ + it2) * 64;
    const bf16 *kp1, *kp2, *vp1, *vp2;
    if (kv0 < MEM_) {
      kp1 = mkp + (size_t)(kv0 + srow1) * HD_ + sc1 * 8;
      kp2 = kp1 + (size_t)32 * HD_;
      vp1 = mvp + (size_t)srow1 * MEM_ + kv0 + sc1 * 8;
      vp2 = vp1 + (size_t)32 * MEM_;
    } else {
      const int t0 = kv0 - MEM_;
      kp1 = kpl + (size_t)(t0 + srow1) * HD_ + sc1 * 8;
      kp2 = kp1 + (size_t)32 * HD_;
      vp1 = vpl + (size_t)srow1 * T_ + t0 + sc1 * 8;
      vp2 = vp1 + (size_t)32 * T_;
    }
    char* kb = KBh + bi * 8192;
    char* vb = VBh + bi * 8192;
    gll16(kp1, kb + t2 * 16);
    gll16(kp2, kb + t2 * 16 + 4096);
    gll16(vp1, vb + t2 * 16);
    gll16(vp2, vb + t2 * 16 + 4096);
  };

  // Q B-frags (k32); fold softmax scale AND log2(e) into Q:
  // s = (q*0.125*log2e) . k  ->  exp2(s) == exp(0.125 * q.k)
  const float QSCALE = 0.125f * 1.44269504089f;
  bf16x8 qf[2][2];
#pragma unroll
  for (int qg = 0; qg < 2; qg++)
#pragma unroll
    for (int hf = 0; hf < 2; hf++) {
      bf16x8 v = *(const bf16x8*)(qbase + (size_t)(qg * 16 + lx) * HD_ +
                                  hf * 32 + quad * 8);
#pragma unroll
      for (int i = 0; i < 8; i++)
        v[i] = (bf16)((float)v[i] * QSCALE);
      qf[qg][hf] = v;
    }

  bf16x8 ones;
#pragma unroll
  for (int i = 0; i < 8; i++) ones[i] = (bf16)1.0f;

  f32x4 o[4][2];
#pragma unroll
  for (int mt = 0; mt < 4; mt++)
#pragma unroll
    for (int qg = 0; qg < 2; qg++) o[mt][qg] = (f32x4){0.f, 0.f, 0.f, 0.f};
  f32x4 osum[2] = {(f32x4){0.f, 0.f, 0.f, 0.f}, (f32x4){0.f, 0.f, 0.f, 0.f}};

  stage(0, 0);   // prologue prefetch

  for (int it = 0; it < NIT2_; it++) {
    const int cur = it & 1;
    if (it + 1 < NIT2_) {
      stage(it + 1, cur ^ 1);
      asm volatile("s_waitcnt vmcnt(4)" ::: "memory");   // cur's 4 loads done
    } else {
      asm volatile("s_waitcnt vmcnt(0)" ::: "memory");
    }
    __builtin_amdgcn_s_barrier();        // all waves' cur parts landed
    __builtin_amdgcn_sched_barrier(0);

    const char* KBc = KBh + cur * 8192;
    const char* VBc = VBh + cur * 8192;
    const int sw = (lx & 7) << 4;   // read-side swizzle (row&7 == lx&7)
    f32x4 s[4][2];
    __builtin_amdgcn_s_setprio(1);
#pragma unroll
    for (int g = 0; g < 4; g++) {
      const char* kb = KBc + (size_t)(g * 16 + lx) * 128;
      bf16x8 ka0 = *(const bf16x8*)(kb + ((quad * 16) ^ sw));
      bf16x8 ka1 = *(const bf16x8*)(kb + ((64 + quad * 16) ^ sw));
#pragma unroll
      for (int qg = 0; qg < 2; qg++) {
        s[g][qg] = (f32x4){0.f, 0.f, 0.f, 0.f};
        s[g][qg] = mfma16(ka0, qf[qg][0], s[g][qg]);
        s[g][qg] = mfma16(ka1, qf[qg][1], s[g][qg]);
      }
    }
    __builtin_amdgcn_s_setprio(0);

    // softmax: p = exp2(s); pack straight into the k32 B-frag halves.
    s16x8 pk[2][2];   // [qg][pair]: elems 0-3 = group 2p, 4-7 = group 2p+1
#pragma unroll
    for (int qg = 0; qg < 2; qg++) {
#pragma unroll
      for (int g = 0; g < 4; g++) {
#pragma unroll
        for (int r = 0; r < 4; r++) {
          float p = __builtin_amdgcn_exp2f(s[g][qg][r]);  // raw v_exp_f32
          pk[qg][g >> 1][(g & 1) * 4 + r] = (short)bf16_bits(p);
        }
      }
    }

    __builtin_amdgcn_s_setprio(1);
#pragma unroll
    for (int mt = 0; mt < 4; mt++) {
      const char* vb = VBc + (size_t)(mt * 16 + lx) * 128;
#pragma unroll
      for (int p = 0; p < 2; p++) {
        // A-frag: ONE b128 — permuted layout put both 4-elem pieces here
        bf16x8 va = *(const bf16x8*)(vb + ((p * 64 + quad * 16) ^ sw));
#pragma unroll
        for (int qg = 0; qg < 2; qg++)
          o[mt][qg] = mfma16(va, __builtin_bit_cast(bf16x8, pk[qg][p]),
                             o[mt][qg]);
      }
    }
    // denominator: osum[qg] += 1^T . P  (all C rows identical)
#pragma unroll
    for (int p = 0; p < 2; p++)
#pragma unroll
      for (int qg = 0; qg < 2; qg++)
        osum[qg] = mfma16(ones, __builtin_bit_cast(bf16x8, pk[qg][p]),
                          osum[qg]);
    __builtin_amdgcn_s_setprio(0);

    __builtin_amdgcn_sched_barrier(0);
    __builtin_amdgcn_s_barrier();   // all waves done reading buf[cur]
  }

  // ---- linear merge of the two kv-halves through the (now dead) K/V LDS ---
  float* OS = (float*)KB;          // 32 KB: half-1 o partials
  float* OSS = (float*)VB;         // 2 KB: half-1 denominators
  if (wh == 1) {
    float* dst = OS + t2 * 32;
#pragma unroll
    for (int mt = 0; mt < 4; mt++)
#pragma unroll
      for (int qg = 0; qg < 2; qg++) {
        int c = mt * 2 + qg;   // chunk 0..7, XOR-spread across banks
        *(f32x4*)(dst + ((c ^ (t2 & 7)) * 4)) = o[mt][qg];
      }
    OSS[t2 * 2 + 0] = osum[0][0];
    OSS[t2 * 2 + 1] = osum[1][0];
  }
  __syncthreads();
  if (wh == 0) {
    const float* src = OS + t2 * 32;
    float inv[2] = {1.f / (osum[0][0] + OSS[t2 * 2 + 0]),
                    1.f / (osum[1][0] + OSS[t2 * 2 + 1])};
#pragma unroll
    for (int qg = 0; qg < 2; qg++) {
#pragma unroll
      for (int mt = 0; mt < 4; mt++) {
        int c = mt * 2 + qg;
        f32x4 po = *(const f32x4*)(src + ((c ^ (t2 & 7)) * 4));
        f32x4 ov;
#pragma unroll
        for (int r = 0; r < 4; r++) ov[r] = (o[mt][qg][r] + po[r]) * inv[qg];
        *(ushort4*)(qbase + (size_t)(qg * 16 + lx) * HD_ + mt * 16 + quad * 4)
            = pack4(ov);
      }
    }
  }
}

// ---------------------------------------------------------------------------
// Scratch plan:
//   ws:    q_ws 0-8M | k_ws 8-16M | vt_ws 16-24M | mem_k 24-25M | mem_vt 25-26M
//          | wob 26-28M (only if ws_size >= 28M; else wob aliases k_ws and is
//          converted AFTER attn by the fallback conv kernel)
//   d_out: xb (bf16 x) 0-8M | wqb (bf16 w_qkv) 8-14M   [dead after gemm1;
//          gemm2 overwrites all of d_out with the real output]
// ---------------------------------------------------------------------------
extern "C" void kernel_launch(void* const* d_in, const int* in_sizes, int n_in,
                              void* d_out, int out_size, void* d_ws,
                              size_t ws_size, hipStream_t stream) {
  const float* x      = (const float*)d_in[0];   // [B,T,D]   f32
  const float* w_qkv  = (const float*)d_in[1];   // [3D,D]    f32
  const float* w_out  = (const float*)d_in[2];   // [D,D]     f32
  const float* b_out  = (const float*)d_in[3];   // [D]       f32
  const float* memory = (const float*)d_in[4];   // [MEM,D]   f32

  char* ws = (char*)d_ws;
  bf16* q_ws   = (bf16*)(ws);                    // [32][2048][64]  8 MiB
  bf16* k_ws   = (bf16*)(ws + (8u << 20));       // [32][2048][64]  8 MiB
  bf16* vt_ws  = (bf16*)(ws + (16u << 20));      // [32][64][2048]  8 MiB
  bf16* mem_k  = (bf16*)(ws + (24u << 20));      // [16][512][64]   1 MiB
  bf16* mem_vt = (bf16*)(ws + (25u << 20));      // [1024][512]     1 MiB
  float* out = (float*)d_out;                    // f32 per reference

  char* outc = (char*)d_out;
  bf16* xb  = (bf16*)(outc);                     // 8 MiB scratch in d_out
  bf16* wqb = (bf16*)(outc + (8u << 20));        // 6 MiB scratch in d_out

  const bool big_ws = ws_size >= (28u << 20);
  bf16* wob = big_ws ? (bf16*)(ws + (26u << 20))   // private 2 MiB
                     : (bf16*)(ws + (8u << 20));   // aliases k_ws (post-attn)

  prep<<<dim3(big_ws ? 4608 : 4096), dim3(256), 0, stream>>>(
      x, w_qkv, memory, w_out, xb, wqb, mem_k, mem_vt, wob);
  gemm_bt<0, false, 128><<<dim3(24, 32), dim3(256), 0, stream>>>(
      xb, wqb, nullptr, q_ws, k_ws, vt_ws, nullptr, 1024);
  attn_kernel<<<dim3(512), dim3(512), 0, stream>>>(
      q_ws, k_ws, vt_ws, mem_k, mem_vt);
  if (!big_ws)
    conv_bf16<<<dim3(512), dim3(256), 0, stream>>>(w_out, wob);
  gemm_bt<1, true, 64><<<dim3(16, 32), dim3(256), 0, stream>>>(
      q_ws, wob, b_out, nullptr, nullptr, nullptr, out, 1024);
}